// Round 4
// baseline (254.149 us; speedup 1.0000x reference)
//
#include <hip/hip_runtime.h>
#include <hip/hip_bf16.h>
#include <math.h>

#define H 24
#define IN 8
#define THREADS 256
#define COLS_PER_BLOCK 1024   // 4 columns per thread

// cst layout in d_ws (floats):
//   [0..191]   Pz[24][8] = softplus(e_p)*softplus(P)
//   [192..383] Pw[24][8] = P (raw)
//   [384..407] Az[24]    = softplus(e)*(softplus(W)@r) + b_z
//   [408..431] Av[24]    = (W@(U*X*r)) + b_v
//   [432..455] V0[24]    = v0

__device__ __forceinline__ float sigm(float v) {
    return 1.0f / (1.0f + __expf(-v));
}
__device__ __forceinline__ float softplus_f(float v) {
    return fmaxf(v, 0.0f) + log1pf(__expf(-fabsf(v)));
}

__global__ __launch_bounds__(256) void precompute_kernel(
        const float* __restrict__ W, const float* __restrict__ P,
        const float* __restrict__ b_v, const float* __restrict__ b_z,
        const float* __restrict__ e, const float* __restrict__ e_p,
        const float* __restrict__ c_x, const float* __restrict__ c_u,
        const float* __restrict__ c_U, const float* __restrict__ v0,
        const float* __restrict__ X0, const float* __restrict__ U0,
        float* __restrict__ cst) {
    __shared__ float rr[H];
    __shared__ float mm[H];
    const int t = threadIdx.x;

    if (t < H) {
        const float r = sigm(v0[t]);
        rr[t] = r;
        const float zx   = 0.001f + 0.099f * sigm(c_x[t]);
        const float Xs   = zx + (1.0f - zx) * X0[t] - U0[t] * X0[t] * r;
        const float zu   = 0.001f + 0.099f * sigm(c_u[t]);
        const float Ucap = 0.9f * sigm(c_U[t]);
        float U = Ucap * zu + (1.0f - zu) * U0[t] + Ucap * (1.0f - U0[t]) * r;
        U = fminf(fmaxf(U, Ucap), 1.0f);
        mm[t] = U * Xs * r;
    }
    __syncthreads();
    if (t < H) {
        const float spe = softplus_f(e[0]);
        float kr = 0.0f, wc = 0.0f;
        #pragma unroll
        for (int j = 0; j < H; ++j) {
            const float w = W[t * H + j];
            kr = fmaf(softplus_f(w), rr[j], kr);
            wc = fmaf(w, mm[j], wc);
        }
        cst[384 + t] = fmaf(spe, kr, b_z[t]);
        cst[408 + t] = wc + b_v[t];
        cst[432 + t] = v0[t];
    }
    for (int k = t; k < H * IN; k += blockDim.x) {
        const float p = P[k];
        cst[k]       = softplus_f(e_p[0]) * softplus_f(p);
        cst[192 + k] = p;
    }
}

// compile-time float4 component extract (j must be an unrolled loop constant)
#define COMP(v, j) ((j) == 0 ? (v).x : (j) == 1 ? (v).y : (j) == 2 ? (v).z : (v).w)

__global__ __launch_bounds__(THREADS) void cbrnn_main_kernel(
        const float* __restrict__ x,    // (IN, B)
        const float* __restrict__ cst,  // 456 floats, uniform -> s_load
        float* __restrict__ out,        // (B, H) row-major
        int B) {
    const int tid = threadIdx.x;
    const long b0 = (long)blockIdx.x * COLS_PER_BLOCK;
    const long c0 = b0 + 4 * (long)tid;

    // ---- coalesced x loads: 4 consecutive columns per thread
    float4 xq[IN];
    if (c0 + 3 < (long)B) {
        #pragma unroll
        for (int i = 0; i < IN; ++i)
            xq[i] = *(const float4*)(x + (long)i * B + c0);
    } else {
        #pragma unroll
        for (int i = 0; i < IN; ++i) {
            float4 t = {0.f, 0.f, 0.f, 0.f};
            const float* row = x + (long)i * B;
            if (c0 + 0 < (long)B) t.x = row[c0 + 0];
            if (c0 + 1 < (long)B) t.y = row[c0 + 1];
            if (c0 + 2 < (long)B) t.z = row[c0 + 2];
            if (c0 + 3 < (long)B) t.w = row[c0 + 3];
            xq[i] = t;
        }
    }

    const float4* cz4  = (const float4*)(cst);         // Pz rows, 2 float4 per h
    const float4* cw4  = (const float4*)(cst + 192);   // Pw rows
    const float4* caz4 = (const float4*)(cst + 384);   // Az quads
    const float4* cav4 = (const float4*)(cst + 408);   // Av quads
    const float4* cv04 = (const float4*)(cst + 432);   // V0 quads

    float* outp = out + c0 * H;   // 384B contiguous per thread

    #pragma unroll
    for (int q = 0; q < 6; ++q) {
        // constants for h = 4q .. 4q+3 (uniform loads -> SGPRs)
        float4 pzv[8], pwv[8];
        #pragma unroll
        for (int hh = 0; hh < 4; ++hh) {
            pzv[2 * hh]     = cz4[(4 * q + hh) * 2];
            pzv[2 * hh + 1] = cz4[(4 * q + hh) * 2 + 1];
            pwv[2 * hh]     = cw4[(4 * q + hh) * 2];
            pwv[2 * hh + 1] = cw4[(4 * q + hh) * 2 + 1];
        }
        const float4 az  = caz4[q];
        const float4 av  = cav4[q];
        const float4 v0q = cv04[q];

        #pragma unroll
        for (int j = 0; j < 4; ++j) {       // column within thread
            float res[4];
            #pragma unroll
            for (int hh = 0; hh < 4; ++hh) { // h within quad
                float sz = COMP(az, hh);
                float sv = COMP(av, hh);
                #pragma unroll
                for (int i = 0; i < 4; ++i) {
                    const float xa = COMP(xq[i], j);
                    const float xb = COMP(xq[4 + i], j);
                    sz = fmaf(COMP(pzv[2 * hh], i), xa, sz);
                    sv = fmaf(COMP(pwv[2 * hh], i), xa, sv);
                    sz = fmaf(COMP(pzv[2 * hh + 1], i), xb, sz);
                    sv = fmaf(COMP(pwv[2 * hh + 1], i), xb, sv);
                }
                const float zt  = sigm(sz);
                const float V0h = COMP(v0q, hh);
                res[hh] = fmaf(0.1f, fmaf(-zt, V0h, sv), V0h);
            }
            if (c0 + j < (long)B) {
                float4 r4 = {res[0], res[1], res[2], res[3]};
                *(float4*)(outp + j * H + 4 * q) = r4;
            }
        }
    }
}

extern "C" void kernel_launch(void* const* d_in, const int* in_sizes, int n_in,
                              void* d_out, int out_size, void* d_ws, size_t ws_size,
                              hipStream_t stream) {
    const float* x   = (const float*)d_in[0];
    const float* W   = (const float*)d_in[1];
    const float* P   = (const float*)d_in[2];
    const float* b_v = (const float*)d_in[3];
    const float* b_z = (const float*)d_in[4];
    const float* e   = (const float*)d_in[5];
    const float* e_p = (const float*)d_in[6];
    const float* c_x = (const float*)d_in[7];
    const float* c_u = (const float*)d_in[8];
    const float* c_U = (const float*)d_in[9];
    const float* v0  = (const float*)d_in[10];
    const float* X0  = (const float*)d_in[11];
    const float* U0  = (const float*)d_in[12];
    float* out = (float*)d_out;
    float* cst = (float*)d_ws;

    const int B = in_sizes[0] / IN;

    precompute_kernel<<<1, 256, 0, stream>>>(W, P, b_v, b_z, e, e_p,
                                             c_x, c_u, c_U, v0, X0, U0, cst);
    const int grid = (B + COLS_PER_BLOCK - 1) / COLS_PER_BLOCK;
    cbrnn_main_kernel<<<grid, THREADS, 0, stream>>>(x, cst, out, B);
}

// Round 5
// 169.166 us; speedup vs baseline: 1.5024x; 1.5024x over previous
//
#include <hip/hip_runtime.h>
#include <hip/hip_bf16.h>
#include <math.h>

#define H 24
#define IN 8
#define THREADS 256

// cst layout in d_ws (floats):
//   [0..191]   Pz[24][8] = softplus(e_p)*softplus(P)
//   [192..383] Pw[24][8] = P (raw)
//   [384..407] Az[24]    = softplus(e)*(softplus(W)@r) + b_z
//   [408..431] Av[24]    = (W@(U*X*r)) + b_v
//   [432..455] V0[24]    = v0

__device__ __forceinline__ float sigm(float v) {
    return 1.0f / (1.0f + __expf(-v));
}
__device__ __forceinline__ float softplus_f(float v) {
    return fmaxf(v, 0.0f) + log1pf(__expf(-fabsf(v)));
}

__global__ __launch_bounds__(256) void precompute_kernel(
        const float* __restrict__ W, const float* __restrict__ P,
        const float* __restrict__ b_v, const float* __restrict__ b_z,
        const float* __restrict__ e, const float* __restrict__ e_p,
        const float* __restrict__ c_x, const float* __restrict__ c_u,
        const float* __restrict__ c_U, const float* __restrict__ v0,
        const float* __restrict__ X0, const float* __restrict__ U0,
        float* __restrict__ cst) {
    __shared__ float rr[H];
    __shared__ float mm[H];
    const int t = threadIdx.x;

    if (t < H) {
        const float r = sigm(v0[t]);
        rr[t] = r;
        const float zx   = 0.001f + 0.099f * sigm(c_x[t]);
        const float Xs   = zx + (1.0f - zx) * X0[t] - U0[t] * X0[t] * r;
        const float zu   = 0.001f + 0.099f * sigm(c_u[t]);
        const float Ucap = 0.9f * sigm(c_U[t]);
        float U = Ucap * zu + (1.0f - zu) * U0[t] + Ucap * (1.0f - U0[t]) * r;
        U = fminf(fmaxf(U, Ucap), 1.0f);
        mm[t] = U * Xs * r;
    }
    __syncthreads();
    if (t < H) {
        const float spe = softplus_f(e[0]);
        float kr = 0.0f, wc = 0.0f;
        #pragma unroll
        for (int j = 0; j < H; ++j) {
            const float w = W[t * H + j];
            kr = fmaf(softplus_f(w), rr[j], kr);
            wc = fmaf(w, mm[j], wc);
        }
        cst[384 + t] = fmaf(spe, kr, b_z[t]);
        cst[408 + t] = wc + b_v[t];
        cst[432 + t] = v0[t];
    }
    for (int k = t; k < H * IN; k += blockDim.x) {
        const float p = P[k];
        cst[k]       = softplus_f(e_p[0]) * softplus_f(p);
        cst[192 + k] = p;
    }
}

// compile-time float4 component extract (idx must be an unrolled-loop constant)
#define COMP(v, j) ((j) == 0 ? (v).x : (j) == 1 ? (v).y : (j) == 2 ? (v).z : (v).w)

__global__ __launch_bounds__(THREADS) void cbrnn_main_kernel(
        const float* __restrict__ x,    // (IN, B)
        const float* __restrict__ cst,  // 456 floats, uniform -> s_load
        float* __restrict__ out,        // (B, H) row-major
        int B) {
    // One column per thread; per-col 96B record in LDS, float4 slots rotated
    // by (col % 6) to break the stride-24-word bank pattern.
    __shared__ float trans[THREADS * H];   // 24 KB, no pad (read side needs density)

    const int tid = threadIdx.x;
    const long b0 = (long)blockIdx.x * THREADS;
    const long col = b0 + tid;

    // ---- coalesced x loads (stride-4B dense per instruction)
    float xv[IN];
    if (col < (long)B) {
        #pragma unroll
        for (int i = 0; i < IN; ++i) xv[i] = x[(long)i * B + col];
    } else {
        #pragma unroll
        for (int i = 0; i < IN; ++i) xv[i] = 0.0f;
    }

    const float4* cz4  = (const float4*)(cst);         // Pz rows: 2 float4/h
    const float4* cw4  = (const float4*)(cst + 192);   // Pw rows
    const float4* caz4 = (const float4*)(cst + 384);
    const float4* cav4 = (const float4*)(cst + 408);
    const float4* cv04 = (const float4*)(cst + 432);

    const int rot = tid % 6;

    #pragma unroll
    for (int q = 0; q < 6; ++q) {
        const float4 az  = caz4[q];
        const float4 av  = cav4[q];
        const float4 v0q = cv04[q];
        float res[4];
        #pragma unroll
        for (int hh = 0; hh < 4; ++hh) {
            const int h = 4 * q + hh;
            const float4 pz0 = cz4[2 * h];
            const float4 pz1 = cz4[2 * h + 1];
            const float4 pw0 = cw4[2 * h];
            const float4 pw1 = cw4[2 * h + 1];
            float sz = COMP(az, hh);
            float sv = COMP(av, hh);
            #pragma unroll
            for (int i = 0; i < 4; ++i) {
                sz = fmaf(COMP(pz0, i), xv[i], sz);
                sv = fmaf(COMP(pw0, i), xv[i], sv);
                sz = fmaf(COMP(pz1, i), xv[4 + i], sz);
                sv = fmaf(COMP(pw1, i), xv[4 + i], sv);
            }
            const float V0h = COMP(v0q, hh);
            res[hh] = fmaf(0.1f, fmaf(-sigm(sz), V0h, sv), V0h);
        }
        int phys = q + rot; if (phys >= 6) phys -= 6;   // rotated slot
        float4 r4 = {res[0], res[1], res[2], res[3]};
        *(float4*)&trans[tid * H + phys * 4] = r4;
    }
    __syncthreads();

    // ---- dense store phase: 1536 float4 = 24 KB contiguous per block
    float4* outbase = (float4*)(out + b0 * H);
    const long nv = ((long)B - b0) * 6;                // valid float4 count
    #pragma unroll
    for (int it = 0; it < 6; ++it) {
        const int k  = it * THREADS + tid;             // 0..1535
        const int c  = k / 6;                          // column within block
        const int jl = k - 6 * c;                      // logical slot
        int phys = jl + (c % 6); if (phys >= 6) phys -= 6;
        const float4 val = *(const float4*)&trans[c * H + phys * 4];
        if ((long)k < nv) outbase[k] = val;
    }
}

extern "C" void kernel_launch(void* const* d_in, const int* in_sizes, int n_in,
                              void* d_out, int out_size, void* d_ws, size_t ws_size,
                              hipStream_t stream) {
    const float* x   = (const float*)d_in[0];
    const float* W   = (const float*)d_in[1];
    const float* P   = (const float*)d_in[2];
    const float* b_v = (const float*)d_in[3];
    const float* b_z = (const float*)d_in[4];
    const float* e   = (const float*)d_in[5];
    const float* e_p = (const float*)d_in[6];
    const float* c_x = (const float*)d_in[7];
    const float* c_u = (const float*)d_in[8];
    const float* c_U = (const float*)d_in[9];
    const float* v0  = (const float*)d_in[10];
    const float* X0  = (const float*)d_in[11];
    const float* U0  = (const float*)d_in[12];
    float* out = (float*)d_out;
    float* cst = (float*)d_ws;

    const int B = in_sizes[0] / IN;

    precompute_kernel<<<1, 256, 0, stream>>>(W, P, b_v, b_z, e, e_p,
                                             c_x, c_u, c_U, v0, X0, U0, cst);
    const int grid = (B + THREADS - 1) / THREADS;
    cbrnn_main_kernel<<<grid, THREADS, 0, stream>>>(x, cst, out, B);
}